// Round 6
// baseline (54.464 us; speedup 1.0000x reference)
//
#include <hip/hip_runtime.h>

typedef __attribute__((ext_vector_type(8))) short short8;
typedef __attribute__((ext_vector_type(4))) float floatx4;
typedef unsigned int uint;
typedef unsigned short ushort;

#define BATCH 16
#define CH 64
#define NPIX 16384   // 128*128
#define TWOC 128
#define XSTR 260     // Xs row stride in dwords: 16B-aligned rows, reads <=2-way banks

__device__ __forceinline__ ushort f2bf(float f) {   // RNE f32 -> bf16 bits
    uint u = __float_as_uint(f);
    u += 0x7FFFu + ((u >> 16) & 1u);
    return (ushort)(u >> 16);
}
__device__ __forceinline__ uint pk2(float lo, float hi) {
    return (uint)f2bf(lo) | ((uint)f2bf(hi) << 16);
}

// ---------------------------------------------------------------------------
// Kernel 1: partial Gram matrices G[b][map][64][64] = sum_n V[c,n]*V[d,n]
// map 0 = template (feeds t_attn, used iff omega!=0)
// map 1 = roi      (feeds r_attn, used iff gamma!=0)
// Early-exits when the corresponding scalar is exactly 0 (contribution is
// exactly zero in that case -- algebraic short-circuit, still deterministic).
// ---------------------------------------------------------------------------
__global__ __launch_bounds__(256) void gram_kernel(
    const float* __restrict__ tmap, const float* __restrict__ rmap,
    const float* __restrict__ gamma, const float* __restrict__ omega,
    float* __restrict__ G)
{
    const int map = blockIdx.y;
    const float mult = (map == 0) ? omega[0] : gamma[0];
    if (mult == 0.f) return;   // wave-uniform: skip dead attention branch

    __shared__ float tile[64][68];
    const int chunk = blockIdx.x;
    const int b     = blockIdx.z;
    const float* x = (map == 0 ? tmap : rmap) + (size_t)b * CH * NPIX + chunk * 512;
    const int t  = threadIdx.x;
    const int ti = t >> 4;
    const int tj = t & 15;

    float acc[4][4];
#pragma unroll
    for (int i = 0; i < 4; ++i)
#pragma unroll
        for (int j = 0; j < 4; ++j) acc[i][j] = 0.f;

    for (int tt = 0; tt < 8; ++tt) {
        const int col0 = tt * 64;
#pragma unroll
        for (int k = 0; k < 16; ++k) {
            int e = t + 256 * k;
            int c = e >> 6, col = e & 63;
            tile[c][col] = x[(size_t)c * NPIX + col0 + col];
        }
        __syncthreads();
#pragma unroll 8
        for (int n = 0; n < 64; n += 2) {
            float2 av[4], bv[4];
#pragma unroll
            for (int i = 0; i < 4; ++i) av[i] = *(const float2*)&tile[ti + 16 * i][n];
#pragma unroll
            for (int j = 0; j < 4; ++j) bv[j] = *(const float2*)&tile[tj + 16 * j][n];
#pragma unroll
            for (int i = 0; i < 4; ++i)
#pragma unroll
                for (int j = 0; j < 4; ++j) {
                    acc[i][j] += av[i].x * bv[j].x;
                    acc[i][j] += av[i].y * bv[j].y;
                }
        }
        __syncthreads();
    }
    float* Gp = G + ((size_t)(b * 2 + map) << 12);
#pragma unroll
    for (int i = 0; i < 4; ++i)
#pragma unroll
        for (int j = 0; j < 4; ++j)
            atomicAdd(&Gp[(ti + 16 * i) * 64 + (tj + 16 * j)], acc[i][j]);
}

// ---------------------------------------------------------------------------
// Kernel 2: per-batch softmax + build mixing matrix, stored as bf16
// A-FRAGMENTS for mfma_f32_16x16x32_bf16:
//   flat idx = ((kstep*4 + mi)*64 + lane)*8 + e
//   holds M[mi*16 + (lane&15)][kstep*32 + (lane>>4)*8 + e]
// where M[o][k] = conv_w[o][k] + (k<64 ? gamma*(W1@r_attn)[o][k]
//                                      : omega*(W2@t_attn)[o][k-64])
// ---------------------------------------------------------------------------
__global__ __launch_bounds__(128) void finalize_kernel(
    const float* __restrict__ G, const float* __restrict__ gamma,
    const float* __restrict__ omega, const float* __restrict__ conv_w,
    ushort* __restrict__ Mtf)
{
    __shared__ float attn[2][64][64];
    const int b = blockIdx.x;
    const int t = threadIdx.x;
    const float gam = gamma[0], om = omega[0];
    {
        const int map = t >> 6, i = t & 63;
        const float need = (map == 0) ? om : gam;
        if (need != 0.f) {
            const float* Grow = G + ((size_t)(b * 2 + map) << 12) + i * 64;
            float mn = Grow[0];
            for (int j = 1; j < 64; ++j) mn = fminf(mn, Grow[j]);
            float s = 0.f;
            for (int j = 0; j < 64; ++j) s += expf(mn - Grow[j]);
            const float inv = 1.f / s;
            for (int j = 0; j < 64; ++j) attn[map][i][j] = expf(mn - Grow[j]) * inv;
        }
    }
    __syncthreads();
    for (int idx = t; idx < 8192; idx += 128) {
        const int e     = idx & 7;
        const int l     = (idx >> 3) & 63;
        const int mi    = (idx >> 9) & 3;
        const int kstep = idx >> 11;
        const int row = mi * 16 + (l & 15);
        const int k   = kstep * 32 + (l >> 4) * 8 + e;
        const float* wrow = conv_w + row * TWOC;
        float v = wrow[k];
        if (k < 64) {
            if (gam != 0.f) {
                float dot = 0.f;
                for (int c = 0; c < 64; ++c) dot += wrow[c] * attn[1][c][k];      // r_attn
                v += gam * dot;
            }
        } else {
            const int d = k - 64;
            if (om != 0.f) {
                float dot = 0.f;
                for (int c = 0; c < 64; ++c) dot += wrow[64 + c] * attn[0][c][d]; // t_attn
                v += om * dot;
            }
        }
        Mtf[(size_t)b * 8192 + idx] = f2bf(v);
    }
}

// ---------------------------------------------------------------------------
// Kernel 3 (MFMA, LDS k-pair transpose):
//   out[b](64 x 16384) = M[b](64x128) @ X(128x16384) + bias
// X rows 0..63 = template channels, 64..127 = roi channels.
//
// Block 256 thr = 4 waves, tile 64 och x 256 px. K in 4 chunks of 32.
// Stage (per chunk): thread handles 4 (kpair p, px-group) items; loads rows
//   2p, 2p+1 as float4 px-rows (each wave instr = 1KB contiguous), packs
//   (bf16(k),bf16(k+1)) uints, ONE ds_write_b128 per item into
//   Xs[p][px] (row stride 260 dwords: 16B-aligned, reads <=2-way banks).
// Compute: A-frags 4x ds_read_b128 from fragment-ordered Ms; B-frags 4x
//   ds_read_b32 (uint j = elems 2j,2j+1, matches short8 LE order); 16 MFMA.
// LDS 16KB Ms + 16.6KB Xs = 33KB; __launch_bounds__(256,4) -> 4 blocks/CU;
// grid 1024 = exactly one residency round; cross-block overlap hides the
// barrier-serial chunk structure; global loads issue before barrier #1.
// ---------------------------------------------------------------------------
__global__ __launch_bounds__(256, 4) void out_kernel(
    const float* __restrict__ tmap, const float* __restrict__ rmap,
    const ushort* __restrict__ Mtf, const float* __restrict__ conv_b,
    float* __restrict__ out)
{
    __shared__ __align__(16) ushort Ms[8192];       // 16 KB: A fragments
    __shared__ __align__(16) uint   Xs[16 * XSTR];  // 16.6 KB: one K=32 chunk

    const int b   = blockIdx.y;
    const int t   = threadIdx.x;
    const int w   = t >> 6;
    const int l   = t & 63;
    const int lg  = l >> 4;
    const int lj  = l & 15;
    const int px0 = blockIdx.x * 256;

    // stage A fragments -> LDS (coalesced uint4 copy; visible after chunk-0 bar2)
    {
        const uint4* src = (const uint4*)(Mtf + (size_t)b * 8192);
        uint4* dst = (uint4*)Ms;
#pragma unroll
        for (int i = 0; i < 4; ++i) dst[t + 256 * i] = src[t + 256 * i];
    }

    floatx4 acc[4][4];
#pragma unroll
    for (int mi = 0; mi < 4; ++mi)
#pragma unroll
        for (int nj = 0; nj < 4; ++nj) acc[mi][nj] = (floatx4){0.f, 0.f, 0.f, 0.f};

    const float* tb = tmap + (size_t)b * CH * NPIX + px0;
    const float* rb = rmap + (size_t)b * CH * NPIX + px0;

#pragma unroll
    for (int c = 0; c < 4; ++c) {
        // chunk c: global k = c*32 .. c*32+31 (c<2: template rows, else roi)
        const float* src = ((c < 2) ? tb : rb) + (size_t)((c & 1) * 32) * NPIX;

        // issue this chunk's global loads (2 px-rows per item, 4 items)
        float4 r0[4], r1[4];
#pragma unroll
        for (int it = 0; it < 4; ++it) {
            const int p = it * 4 + w;               // kpair 0..15
            r0[it] = *(const float4*)&src[(size_t)(2 * p) * NPIX + 4 * l];
            r1[it] = *(const float4*)&src[(size_t)(2 * p + 1) * NPIX + 4 * l];
        }
        __syncthreads();   // prior chunk's Xs reads complete (loads overlap this wait)

#pragma unroll
        for (int it = 0; it < 4; ++it) {
            const int p = it * 4 + w;
            uint4 o;
            o.x = pk2(r0[it].x, r1[it].x);
            o.y = pk2(r0[it].y, r1[it].y);
            o.z = pk2(r0[it].z, r1[it].z);
            o.w = pk2(r0[it].w, r1[it].w);
            *(uint4*)&Xs[p * XSTR + 4 * l] = o;
        }
        __syncthreads();   // Xs (and, c==0, Ms) visible

        short8 a[4];
#pragma unroll
        for (int mi = 0; mi < 4; ++mi)
            a[mi] = *(const short8*)&Ms[((c * 4 + mi) * 64 + l) * 8];

#pragma unroll
        for (int nj = 0; nj < 4; ++nj) {
            const int pxl = w * 64 + nj * 16 + lj;  // px within block tile
            uint4 bu;
            bu.x = Xs[(4 * lg + 0) * XSTR + pxl];
            bu.y = Xs[(4 * lg + 1) * XSTR + pxl];
            bu.z = Xs[(4 * lg + 2) * XSTR + pxl];
            bu.w = Xs[(4 * lg + 3) * XSTR + pxl];
            const short8 bb = *(const short8*)&bu;
#pragma unroll
            for (int mi = 0; mi < 4; ++mi)
                acc[mi][nj] = __builtin_amdgcn_mfma_f32_16x16x32_bf16(
                    a[mi], bb, acc[mi][nj], 0, 0, 0);
        }
    }

    // epilogue: C/D layout col=lane&15, row=(lane>>4)*4+reg (guide m89/m91)
    const int pxw = px0 + w * 64;
#pragma unroll
    for (int mi = 0; mi < 4; ++mi) {
#pragma unroll
        for (int r = 0; r < 4; ++r) {
            const int och = mi * 16 + lg * 4 + r;
            const float bv = conv_b[och];
            float* orow = out + ((size_t)b * CH + och) * NPIX;
#pragma unroll
            for (int nj = 0; nj < 4; ++nj)
                orow[pxw + nj * 16 + lj] = acc[mi][nj][r] + bv;
        }
    }
}

// ---------------------------------------------------------------------------
extern "C" void kernel_launch(void* const* d_in, const int* in_sizes, int n_in,
                              void* d_out, int out_size, void* d_ws, size_t ws_size,
                              hipStream_t stream) {
    const float* tmap   = (const float*)d_in[0];
    const float* rmap   = (const float*)d_in[1];
    const float* gamma  = (const float*)d_in[2];
    const float* omega  = (const float*)d_in[3];
    const float* conv_w = (const float*)d_in[4];
    const float* conv_b = (const float*)d_in[5];
    float* out = (float*)d_out;

    // ws layout: G [16][2][4096] fp32 (512 KiB), then Mtf [16][8192] bf16 (256 KiB)
    float*  G   = (float*)d_ws;
    ushort* Mtf = (ushort*)((char*)d_ws + (size_t)BATCH * 2 * 4096 * sizeof(float));

    hipMemsetAsync(d_ws, 0, (size_t)BATCH * 2 * 4096 * sizeof(float), stream);

    gram_kernel<<<dim3(32, 2, BATCH), 256, 0, stream>>>(tmap, rmap, gamma, omega, G);
    finalize_kernel<<<dim3(BATCH), 128, 0, stream>>>(G, gamma, omega, conv_w, Mtf);
    out_kernel<<<dim3(64, BATCH), 256, 0, stream>>>(tmap, rmap, Mtf, conv_b, out);
}